// Round 2
// baseline (158.584 us; speedup 1.0000x reference)
//
#include <hip/hip_runtime.h>

// LSTM_WP: B=4096 batch-1 LSTMs, T=H=128, input_size=1, fused MFMA-f16 recurrence.
// Round 12: keep r11 (swapped operands, packed ew, C pre-scaled by 2log2e,
// prep folded into init, 256 blocks x 16 batches, 8 waves, 1 barrier/step).
// This round: serial-tail surgery only —
//  (1) per-gate depth-2 + merge + exp interleave: gate g's 4 exps issue in
//      gate g+1's MFMA shadow; post-MFMA tail is now 4 exps + phase2 instead
//      of 16 exps + phase2.
//  (2) preact refill moved into the post-barrier ds_read latency hole
//      (depends only on xs -> fills the ~120-cycle window after the barrier).
//  (3) h store split into 2x f16x2 (4 B) writes, one per phase-2 pair, so the
//      first write issues ~40 cycles before the second chain retires.

#define H   128
#define T   128
#define BLOCK 512
#define HSTRIDE 136     // f16 per h row: 272 B -> b128-aligned, 2-way banks (free)
#define XSTRIDE 20      // f32 per xs row: 80 B
#define LOG2E    1.44269504088896340736f
#define TWOLOG2E 2.88539008177792681472f

typedef _Float16 f16x8 __attribute__((ext_vector_type(8)));
typedef _Float16 f16x2 __attribute__((ext_vector_type(2)));
typedef float    f32x4 __attribute__((ext_vector_type(4)));
typedef float    f32x2 __attribute__((ext_vector_type(2)));

__device__ __forceinline__ float frcp(float v)  { return __builtin_amdgcn_rcpf(v); }
__device__ __forceinline__ float fexp2(float v) { return __builtin_amdgcn_exp2f(v); }

// ---- one LSTM step: 16 batches x this wave's 16 cols, transposed fragments ----
// D[row=gatecol-in-tile][col=batch]: lane(l15,q) holds gatecols hcol0..hcol0+3
// of batch l15. iv: preacts for THIS step (in); refilled for NEXT step (out).
__device__ __forceinline__ void lstm_step(const _Float16* __restrict__ hr,
                                          _Float16* __restrict__ hw,
                                          f32x4 iv[4], const float* xp_next,
                                          const f16x8 wf[4][4],
                                          const f32x4 wihv[4], const f32x4 biasv[4],
                                          f32x2 C[2], int l15, int q, int hcol0)
{
    // B-fragments (h): 4x ds_read_b128, issued back-to-back
    const _Float16* ar = hr + l15 * HSTRIDE + q * 8;
    f16x8 af0 = *(const f16x8*)(ar);
    f16x8 af1 = *(const f16x8*)(ar + 32);
    f16x8 af2 = *(const f16x8*)(ar + 64);
    f16x8 af3 = *(const f16x8*)(ar + 96);

    // depth-1 of all 8 chains (needs only af0/af2)
    const f32x4 zz = {0.f, 0.f, 0.f, 0.f};
    f32x4 lo[4], hi[4];
    #pragma unroll
    for (int g = 0; g < 4; ++g) {
        lo[g] = __builtin_amdgcn_mfma_f32_16x16x32_f16(wf[g][0], af0, iv[g], 0, 0, 0);
        hi[g] = __builtin_amdgcn_mfma_f32_16x16x32_f16(wf[g][2], af2, zz,    0, 0, 0);
    }

    // next step's preacts: depends only on xs -> fills the ds_read latency
    // hole after the barrier / the depth-1 MFMA shadow
    {
        float xv = xp_next[l15];
        f32x4 xb = {xv, xv, xv, xv};
        #pragma unroll
        for (int g = 0; g < 4; ++g)
            iv[g] = __builtin_elementwise_fma(xb, wihv[g], biasv[g]);
    }

    // depth-2 + merge + exps per gate: gate g's trans issue under gate g+1's MFMAs
    f32x2 E[4][2];
    #pragma unroll
    for (int g = 0; g < 4; ++g) {
        f32x4 a = __builtin_amdgcn_mfma_f32_16x16x32_f16(wf[g][1], af1, lo[g], 0, 0, 0);
        f32x4 b = __builtin_amdgcn_mfma_f32_16x16x32_f16(wf[g][3], af3, hi[g], 0, 0, 0);
        f32x4 acc = a + b;
        if (g == 2) {   // tanh gate: positive exponent
            E[g][0] = (f32x2){ fexp2( acc[0]), fexp2( acc[1]) };
            E[g][1] = (f32x2){ fexp2( acc[2]), fexp2( acc[3]) };
        } else {        // sigmoid gates: negative exponent (free input modifier)
            E[g][0] = (f32x2){ fexp2(-acc[0]), fexp2(-acc[1]) };
            E[g][1] = (f32x2){ fexp2(-acc[2]), fexp2(-acc[3]) };
        }
    }

    // ---- ew phase 2: packed-f32 pairs; C kept pre-scaled by 2log2e ----
    const f32x2 one2 = {1.0f, 1.0f};
    const f32x2 k2   = { TWOLOG2E,  TWOLOG2E};
    const f32x2 mk2  = {-TWOLOG2E, -TWOLOG2E};
    _Float16* hwp = hw + l15 * HSTRIDE + hcol0;
    #pragma unroll
    for (int p = 0; p < 2; ++p) {
        f32x2 u  = one2 + E[0][p];                               // 1+Ei
        f32x2 v  = one2 + E[1][p];                               // 1+Ef
        f32x2 w  = one2 + E[2][p];                               // 1+Eg
        f32x2 wm = __builtin_elementwise_fma(E[2][p], k2, mk2);  // 2log2e*(Eg-1)
        f32x2 uw = u * w;
        // C' = [C*u*w + wm*v] / (v*u*w)  (2log2e domain), one rcp
        f32x2 nm = __builtin_elementwise_fma(C[p], uw, wm * v);
        f32x2 dn = v * uw;
        f32x2 rd = { frcp(dn[0]), frcp(dn[1]) };
        f32x2 cn = nm * rd;
        C[p] = cn;
        f32x2 ec  = { fexp2(cn[0]), fexp2(cn[1]) };              // tanh(c') = (ec-1)/(ec+1)
        f32x2 den = (ec + one2) * (one2 + E[3][p]);
        f32x2 rh  = { frcp(den[0]), frcp(den[1]) };
        f32x2 hv  = (ec - one2) * rh;
        // early 4 B store per pair: p=0 drains before p=1's chain retires
        f16x2 hh = { (_Float16)hv[0], (_Float16)hv[1] };
        *(f16x2*)(hwp + 2 * p) = hh;
    }
}

__launch_bounds__(BLOCK, 2)
__global__ void lstm_fused_kernel(const float* __restrict__ x,
                                  const float* __restrict__ W_ih,
                                  const float* __restrict__ W_hh,
                                  const float* __restrict__ b_ih,
                                  const float* __restrict__ b_hh,
                                  const float* __restrict__ fc_W,
                                  const float* __restrict__ fc_b,
                                  float* __restrict__ out)
{
    __shared__ __align__(16) float xs[T + 1][XSTRIDE];           // +1 row: prefetch pad
    __shared__ __align__(16) _Float16 hb0[16 * HSTRIDE];         // h buffers (4.25 KB each)
    __shared__ __align__(16) _Float16 hb1[16 * HSTRIDE];

    const int tid  = threadIdx.x;
    const int wave = tid >> 6;          // column tile 0..7
    const int lane = tid & 63;
    const int l15  = lane & 15;         // batch row (B-operand col)
    const int q    = lane >> 4;         // 0..3
    const int hcol0 = wave * 16 + q * 4;// first of this lane's 4 hidden cols

    // ---- stage x: [b][t] global -> xs[t][b] (16 batches x 128 t) ----
    {
        const int t0 = tid & 127;
        const int bb = tid >> 7;        // 0..3
        const float* xb = x + (size_t)blockIdx.x * (16 * T);
        xs[t0][bb]      = xb[bb * T + t0];
        xs[t0][bb + 4]  = xb[(bb + 4) * T + t0];
        xs[t0][bb + 8]  = xb[(bb + 8) * T + t0];
        xs[t0][bb + 12] = xb[(bb + 12) * T + t0];
    }
    for (int i = tid; i < 16 * HSTRIDE; i += BLOCK)              // h0 = 0
        hb0[i] = (_Float16)0.0f;

    // ---- weights: fragments built directly from W_hh (prep folded in).
    // lane(l15,q), kc -> W_hh[g*H + wave*16 + l15][kc*32+q*8 ..+8], log2e-scaled
    f16x8 wf[4][4];
    f32x4 wihv[4], biasv[4];
    #pragma unroll
    for (int g = 0; g < 4; ++g) {
        const float s = (g == 2) ? TWOLOG2E : LOG2E;
        #pragma unroll
        for (int kc = 0; kc < 4; ++kc) {
            const float* src = W_hh + (size_t)(g * H + wave * 16 + l15) * H + kc * 32 + q * 8;
            float4 w0 = *(const float4*)src;
            float4 w1 = *(const float4*)(src + 4);
            f16x8 f;
            f[0] = (_Float16)(w0.x * s); f[1] = (_Float16)(w0.y * s);
            f[2] = (_Float16)(w0.z * s); f[3] = (_Float16)(w0.w * s);
            f[4] = (_Float16)(w1.x * s); f[5] = (_Float16)(w1.y * s);
            f[6] = (_Float16)(w1.z * s); f[7] = (_Float16)(w1.w * s);
            wf[g][kc] = f;
        }
        #pragma unroll
        for (int r = 0; r < 4; ++r) {   // per-lane input-proj coeffs for its 4 cols
            const int n = g * H + hcol0 + r;
            wihv[g][r]  = W_ih[n] * s;
            biasv[g][r] = (b_ih[n] + b_hh[n]) * s;
        }
    }

    f32x2 C[2] = {{0.f, 0.f}, {0.f, 0.f}};   // cell state, pre-scaled by 2log2e

    __syncthreads();

    // preacts for t=0
    f32x4 iv[4];
    {
        float xv = xs[0][l15];
        f32x4 xb = {xv, xv, xv, xv};
        #pragma unroll
        for (int g = 0; g < 4; ++g)
            iv[g] = __builtin_elementwise_fma(xb, wihv[g], biasv[g]);
    }
    const float* xpn = &xs[1][0];       // next-step preact source

    // ---- recurrence: unrolled x2, compile-time buffer bases, 1 barrier/step ----
    #pragma unroll 1
    for (int t2 = 0; t2 < T / 2; ++t2) {
        lstm_step(hb0, hb1, iv, xpn, wf, wihv, biasv, C, l15, q, hcol0);
        xpn += XSTRIDE;
        __syncthreads();
        lstm_step(hb1, hb0, iv, xpn, wf, wihv, biasv, C, l15, q, hcol0);
        xpn += XSTRIDE;
        __syncthreads();
    }
    // T even -> final h lives in hb0

    // ---- epilogue: out[b] = fc_b + sum_j fc_W[j] * hT[b][j] ----
    if (tid < 256) {
        const int b    = tid >> 4;      // 0..15
        const int part = tid & 15;
        const _Float16* hrow = &hb0[b * HSTRIDE];
        float s = 0.0f;
        #pragma unroll
        for (int i = 0; i < 8; ++i) {
            const int j = part * 8 + i;
            s += fc_W[j] * (float)hrow[j];
        }
        s += __shfl_xor(s, 8, 16);
        s += __shfl_xor(s, 4, 16);
        s += __shfl_xor(s, 2, 16);
        s += __shfl_xor(s, 1, 16);
        if (part == 0)
            out[blockIdx.x * 16 + b] = s + fc_b[0];
    }
}

extern "C" void kernel_launch(void* const* d_in, const int* in_sizes, int n_in,
                              void* d_out, int out_size, void* d_ws, size_t ws_size,
                              hipStream_t stream)
{
    const float* x    = (const float*)d_in[0];
    const float* W_ih = (const float*)d_in[1];
    const float* W_hh = (const float*)d_in[2];
    const float* b_ih = (const float*)d_in[3];
    const float* b_hh = (const float*)d_in[4];
    const float* fc_W = (const float*)d_in[5];
    const float* fc_b = (const float*)d_in[6];
    float* out = (float*)d_out;
    (void)d_ws; (void)ws_size;

    const int B = in_sizes[0] / H;         // 4096 chunks
    dim3 grid(B / 16);                     // 256 blocks -> 1 per CU
    dim3 block(BLOCK);                     // 8 waves, 2 per SIMD
    hipLaunchKernelGGL(lstm_fused_kernel, grid, block, 0, stream,
                       x, W_ih, W_hh, b_ih, b_hh, fc_W, fc_b, out);
}

// Round 4
// 157.535 us; speedup vs baseline: 1.0067x; 1.0067x over previous
//
#include <hip/hip_runtime.h>

// LSTM_WP: B=4096 batch-1 LSTMs, T=H=128, input_size=1, fused MFMA-f16 recurrence.
// Round 14: REVERT to r12 (known-good, 113.2 us kernel). r13's forced-VOP3P
// inline asm mis-executed (absmax 1.5e-2 = one h-column wrong by O(0.5),
// diluted by fc_W~0.03 — a miscompile, not rounding drift; the contractive
// recurrence pins reassociation noise at the f16-ulp floor 4.88e-4).
// Cycle model (1.4 GHz, 1237 cyc/step/SIMD): MFMA 310 (FLOP-exact floor),
// VALU 594 = 297/wave vs ~300 modeled floor (28 trans x4 + ~70 pk x2 + misc)
// => hipcc ALREADY forms v_pk_*_f32 from the f32x2 IR; no VALU fat remains.
// Remaining 27% stall = all-to-all h-exchange barrier; two-barrier wave-group
// stagger provably lengthens the critical path (producer-gates-everyone).
// Design space pinned: 4096 = 256 CU x 16 batches, MFMA 16x16 pins
// 16 cols/wave x 8 waves. This structure is the session's floor.
// Only change vs r12: u32-vectorized h0 zero-init (one-time, zero risk).

#define H   128
#define T   128
#define BLOCK 512
#define HSTRIDE 136     // f16 per h row: 272 B -> b128-aligned, 2-way banks (free)
#define XSTRIDE 20      // f32 per xs row: 80 B
#define LOG2E    1.44269504088896340736f
#define TWOLOG2E 2.88539008177792681472f

typedef _Float16 f16x8 __attribute__((ext_vector_type(8)));
typedef _Float16 f16x2 __attribute__((ext_vector_type(2)));
typedef float    f32x4 __attribute__((ext_vector_type(4)));
typedef float    f32x2 __attribute__((ext_vector_type(2)));

__device__ __forceinline__ float frcp(float v)  { return __builtin_amdgcn_rcpf(v); }
__device__ __forceinline__ float fexp2(float v) { return __builtin_amdgcn_exp2f(v); }

// ---- one LSTM step: 16 batches x this wave's 16 cols, transposed fragments ----
// D[row=gatecol-in-tile][col=batch]: lane(l15,q) holds gatecols hcol0..hcol0+3
// of batch l15. iv: preacts for THIS step (in); refilled for NEXT step (out).
__device__ __forceinline__ void lstm_step(const _Float16* __restrict__ hr,
                                          _Float16* __restrict__ hw,
                                          f32x4 iv[4], const float* xp_next,
                                          const f16x8 wf[4][4],
                                          const f32x4 wihv[4], const f32x4 biasv[4],
                                          f32x2 C[2], int l15, int q, int hcol0)
{
    // B-fragments (h): 4x ds_read_b128, issued back-to-back
    const _Float16* ar = hr + l15 * HSTRIDE + q * 8;
    f16x8 af0 = *(const f16x8*)(ar);
    f16x8 af1 = *(const f16x8*)(ar + 32);
    f16x8 af2 = *(const f16x8*)(ar + 64);
    f16x8 af3 = *(const f16x8*)(ar + 96);

    // depth-1 of all 8 chains (needs only af0/af2)
    const f32x4 zz = {0.f, 0.f, 0.f, 0.f};
    f32x4 lo[4], hi[4];
    #pragma unroll
    for (int g = 0; g < 4; ++g) {
        lo[g] = __builtin_amdgcn_mfma_f32_16x16x32_f16(wf[g][0], af0, iv[g], 0, 0, 0);
        hi[g] = __builtin_amdgcn_mfma_f32_16x16x32_f16(wf[g][2], af2, zz,    0, 0, 0);
    }

    // next step's preacts: depends only on xs -> fills the ds_read latency
    // hole after the barrier / the depth-1 MFMA shadow
    {
        float xv = xp_next[l15];
        f32x4 xb = {xv, xv, xv, xv};
        #pragma unroll
        for (int g = 0; g < 4; ++g)
            iv[g] = __builtin_elementwise_fma(xb, wihv[g], biasv[g]);
    }

    // depth-2 + merge + exps per gate: gate g's trans issue under gate g+1's MFMAs
    f32x2 E[4][2];
    #pragma unroll
    for (int g = 0; g < 4; ++g) {
        f32x4 a = __builtin_amdgcn_mfma_f32_16x16x32_f16(wf[g][1], af1, lo[g], 0, 0, 0);
        f32x4 b = __builtin_amdgcn_mfma_f32_16x16x32_f16(wf[g][3], af3, hi[g], 0, 0, 0);
        f32x4 acc = a + b;
        if (g == 2) {   // tanh gate: positive exponent
            E[g][0] = (f32x2){ fexp2( acc[0]), fexp2( acc[1]) };
            E[g][1] = (f32x2){ fexp2( acc[2]), fexp2( acc[3]) };
        } else {        // sigmoid gates: negated exponent (free src modifier)
            E[g][0] = (f32x2){ fexp2(-acc[0]), fexp2(-acc[1]) };
            E[g][1] = (f32x2){ fexp2(-acc[2]), fexp2(-acc[3]) };
        }
    }

    // ---- ew phase 2: packed-f32 pairs; C kept pre-scaled by 2log2e ----
    const f32x2 one2 = {1.0f, 1.0f};
    const f32x2 k2   = { TWOLOG2E,  TWOLOG2E};
    const f32x2 mk2  = {-TWOLOG2E, -TWOLOG2E};
    _Float16* hwp = hw + l15 * HSTRIDE + hcol0;
    #pragma unroll
    for (int p = 0; p < 2; ++p) {
        f32x2 u  = one2 + E[0][p];                               // 1+Ei
        f32x2 v  = one2 + E[1][p];                               // 1+Ef
        f32x2 w  = one2 + E[2][p];                               // 1+Eg
        f32x2 wm = __builtin_elementwise_fma(E[2][p], k2, mk2);  // 2log2e*(Eg-1)
        f32x2 uw = u * w;
        // C' = [C*u*w + wm*v] / (v*u*w)  (2log2e domain), one rcp
        f32x2 nm = __builtin_elementwise_fma(C[p], uw, wm * v);
        f32x2 dn = v * uw;
        f32x2 rd = { frcp(dn[0]), frcp(dn[1]) };
        f32x2 cn = nm * rd;
        C[p] = cn;
        f32x2 ec  = { fexp2(cn[0]), fexp2(cn[1]) };              // tanh(c') = (ec-1)/(ec+1)
        f32x2 den = (ec + one2) * (one2 + E[3][p]);
        f32x2 rh  = { frcp(den[0]), frcp(den[1]) };
        f32x2 hv  = (ec - one2) * rh;
        // early 4 B store per pair: p=0 drains before p=1's chain retires
        f16x2 hh = { (_Float16)hv[0], (_Float16)hv[1] };
        *(f16x2*)(hwp + 2 * p) = hh;
    }
}

__launch_bounds__(BLOCK, 2)
__global__ void lstm_fused_kernel(const float* __restrict__ x,
                                  const float* __restrict__ W_ih,
                                  const float* __restrict__ W_hh,
                                  const float* __restrict__ b_ih,
                                  const float* __restrict__ b_hh,
                                  const float* __restrict__ fc_W,
                                  const float* __restrict__ fc_b,
                                  float* __restrict__ out)
{
    __shared__ __align__(16) float xs[T + 1][XSTRIDE];           // +1 row: prefetch pad
    __shared__ __align__(16) _Float16 hb0[16 * HSTRIDE];         // h buffers (4.25 KB each)
    __shared__ __align__(16) _Float16 hb1[16 * HSTRIDE];

    const int tid  = threadIdx.x;
    const int wave = tid >> 6;          // column tile 0..7
    const int lane = tid & 63;
    const int l15  = lane & 15;         // batch row (B-operand col)
    const int q    = lane >> 4;         // 0..3
    const int hcol0 = wave * 16 + q * 4;// first of this lane's 4 hidden cols

    // ---- stage x: [b][t] global -> xs[t][b] (16 batches x 128 t) ----
    {
        const int t0 = tid & 127;
        const int bb = tid >> 7;        // 0..3
        const float* xb = x + (size_t)blockIdx.x * (16 * T);
        xs[t0][bb]      = xb[bb * T + t0];
        xs[t0][bb + 4]  = xb[(bb + 4) * T + t0];
        xs[t0][bb + 8]  = xb[(bb + 8) * T + t0];
        xs[t0][bb + 12] = xb[(bb + 12) * T + t0];
    }
    // h0 = 0 (u32-vectorized: 1088 dword stores across 512 threads)
    for (int i = tid; i < 16 * HSTRIDE / 2; i += BLOCK)
        ((unsigned int*)hb0)[i] = 0u;

    // ---- weights: fragments built directly from W_hh (prep folded in).
    // lane(l15,q), kc -> W_hh[g*H + wave*16 + l15][kc*32+q*8 ..+8], log2e-scaled
    f16x8 wf[4][4];
    f32x4 wihv[4], biasv[4];
    #pragma unroll
    for (int g = 0; g < 4; ++g) {
        const float s = (g == 2) ? TWOLOG2E : LOG2E;
        #pragma unroll
        for (int kc = 0; kc < 4; ++kc) {
            const float* src = W_hh + (size_t)(g * H + wave * 16 + l15) * H + kc * 32 + q * 8;
            float4 w0 = *(const float4*)src;
            float4 w1 = *(const float4*)(src + 4);
            f16x8 f;
            f[0] = (_Float16)(w0.x * s); f[1] = (_Float16)(w0.y * s);
            f[2] = (_Float16)(w0.z * s); f[3] = (_Float16)(w0.w * s);
            f[4] = (_Float16)(w1.x * s); f[5] = (_Float16)(w1.y * s);
            f[6] = (_Float16)(w1.z * s); f[7] = (_Float16)(w1.w * s);
            wf[g][kc] = f;
        }
        #pragma unroll
        for (int r = 0; r < 4; ++r) {   // per-lane input-proj coeffs for its 4 cols
            const int n = g * H + hcol0 + r;
            wihv[g][r]  = W_ih[n] * s;
            biasv[g][r] = (b_ih[n] + b_hh[n]) * s;
        }
    }

    f32x2 C[2] = {{0.f, 0.f}, {0.f, 0.f}};   // cell state, pre-scaled by 2log2e

    __syncthreads();

    // preacts for t=0
    f32x4 iv[4];
    {
        float xv = xs[0][l15];
        f32x4 xb = {xv, xv, xv, xv};
        #pragma unroll
        for (int g = 0; g < 4; ++g)
            iv[g] = __builtin_elementwise_fma(xb, wihv[g], biasv[g]);
    }
    const float* xpn = &xs[1][0];       // next-step preact source

    // ---- recurrence: unrolled x2, compile-time buffer bases, 1 barrier/step ----
    #pragma unroll 1
    for (int t2 = 0; t2 < T / 2; ++t2) {
        lstm_step(hb0, hb1, iv, xpn, wf, wihv, biasv, C, l15, q, hcol0);
        xpn += XSTRIDE;
        __syncthreads();
        lstm_step(hb1, hb0, iv, xpn, wf, wihv, biasv, C, l15, q, hcol0);
        xpn += XSTRIDE;
        __syncthreads();
    }
    // T even -> final h lives in hb0

    // ---- epilogue: out[b] = fc_b + sum_j fc_W[j] * hT[b][j] ----
    if (tid < 256) {
        const int b    = tid >> 4;      // 0..15
        const int part = tid & 15;
        const _Float16* hrow = &hb0[b * HSTRIDE];
        float s = 0.0f;
        #pragma unroll
        for (int i = 0; i < 8; ++i) {
            const int j = part * 8 + i;
            s += fc_W[j] * (float)hrow[j];
        }
        s += __shfl_xor(s, 8, 16);
        s += __shfl_xor(s, 4, 16);
        s += __shfl_xor(s, 2, 16);
        s += __shfl_xor(s, 1, 16);
        if (part == 0)
            out[blockIdx.x * 16 + b] = s + fc_b[0];
    }
}

extern "C" void kernel_launch(void* const* d_in, const int* in_sizes, int n_in,
                              void* d_out, int out_size, void* d_ws, size_t ws_size,
                              hipStream_t stream)
{
    const float* x    = (const float*)d_in[0];
    const float* W_ih = (const float*)d_in[1];
    const float* W_hh = (const float*)d_in[2];
    const float* b_ih = (const float*)d_in[3];
    const float* b_hh = (const float*)d_in[4];
    const float* fc_W = (const float*)d_in[5];
    const float* fc_b = (const float*)d_in[6];
    float* out = (float*)d_out;
    (void)d_ws; (void)ws_size;

    const int B = in_sizes[0] / H;         // 4096 chunks
    dim3 grid(B / 16);                     // 256 blocks -> 1 per CU
    dim3 block(BLOCK);                     // 8 waves, 2 per SIMD
    hipLaunchKernelGGL(lstm_fused_kernel, grid, block, 0, stream,
                       x, W_ih, W_hh, b_ih, b_hh, fc_W, fc_b, out);
}

// Round 6
// 156.819 us; speedup vs baseline: 1.0113x; 1.0046x over previous
//
#include <hip/hip_runtime.h>

// LSTM_WP: B=4096 batch-1 LSTMs, T=H=128, input_size=1, fused MFMA-f16 recurrence.
// Round 16: r15 with the compile fix — __builtin_amdgcn_cvt_pkrtz returns
// __fp16x2, bit-cast to our _Float16-based f16x2 for the LDS store.
//  (1) fma-folds in the h tail: (ec+1)*(1+Eo) -> fma(ec,eo1,eo1);
//      (ec-1)*rh -> fma(ec,rh,-rh). -4 pk/step/wave, shorter serial tail.
//  (2) v_cvt_pkrtz_f16_f32 via builtin for the h store (1 op instead of 2-3).
// Cycle model (1.4 GHz, ~1237 cyc/step/SIMD): MFMA 322 (FLOP-exact floor),
// VALU ~600 (trans 28x4 + pk ~44x2 per wave = algorithmic floor), stall ~300
// (two-wave lockstep drain; TLP pinned at 2 waves/SIMD by 4096 = 256 CU x 16).
// If this lands <=1%, the structure is at its latency floor.

#define H   128
#define T   128
#define BLOCK 512
#define HSTRIDE 136     // f16 per h row: 272 B -> b128-aligned, 2-way banks (free)
#define XSTRIDE 20      // f32 per xs row: 80 B
#define LOG2E    1.44269504088896340736f
#define TWOLOG2E 2.88539008177792681472f

typedef _Float16 f16x8 __attribute__((ext_vector_type(8)));
typedef _Float16 f16x2 __attribute__((ext_vector_type(2)));
typedef __fp16   h16x2 __attribute__((ext_vector_type(2)));   // cvt_pkrtz return type
typedef float    f32x4 __attribute__((ext_vector_type(4)));
typedef float    f32x2 __attribute__((ext_vector_type(2)));

__device__ __forceinline__ float frcp(float v)  { return __builtin_amdgcn_rcpf(v); }
__device__ __forceinline__ float fexp2(float v) { return __builtin_amdgcn_exp2f(v); }

// ---- one LSTM step: 16 batches x this wave's 16 cols, transposed fragments ----
// D[row=gatecol-in-tile][col=batch]: lane(l15,q) holds gatecols hcol0..hcol0+3
// of batch l15. iv: preacts for THIS step (in); refilled for NEXT step (out).
__device__ __forceinline__ void lstm_step(const _Float16* __restrict__ hr,
                                          _Float16* __restrict__ hw,
                                          f32x4 iv[4], const float* xp_next,
                                          const f16x8 wf[4][4],
                                          const f32x4 wihv[4], const f32x4 biasv[4],
                                          f32x2 C[2], int l15, int q, int hcol0)
{
    // B-fragments (h): 4x ds_read_b128, issued back-to-back
    const _Float16* ar = hr + l15 * HSTRIDE + q * 8;
    f16x8 af0 = *(const f16x8*)(ar);
    f16x8 af1 = *(const f16x8*)(ar + 32);
    f16x8 af2 = *(const f16x8*)(ar + 64);
    f16x8 af3 = *(const f16x8*)(ar + 96);

    // depth-1 of all 8 chains (needs only af0/af2)
    const f32x4 zz = {0.f, 0.f, 0.f, 0.f};
    f32x4 lo[4], hi[4];
    #pragma unroll
    for (int g = 0; g < 4; ++g) {
        lo[g] = __builtin_amdgcn_mfma_f32_16x16x32_f16(wf[g][0], af0, iv[g], 0, 0, 0);
        hi[g] = __builtin_amdgcn_mfma_f32_16x16x32_f16(wf[g][2], af2, zz,    0, 0, 0);
    }

    // next step's preacts: depends only on xs -> fills the ds_read latency
    // hole after the barrier / the depth-1 MFMA shadow
    {
        float xv = xp_next[l15];
        f32x4 xb = {xv, xv, xv, xv};
        #pragma unroll
        for (int g = 0; g < 4; ++g)
            iv[g] = __builtin_elementwise_fma(xb, wihv[g], biasv[g]);
    }

    // depth-2 + merge + exps per gate: gate g's trans issue under gate g+1's MFMAs
    f32x2 E[4][2];
    #pragma unroll
    for (int g = 0; g < 4; ++g) {
        f32x4 a = __builtin_amdgcn_mfma_f32_16x16x32_f16(wf[g][1], af1, lo[g], 0, 0, 0);
        f32x4 b = __builtin_amdgcn_mfma_f32_16x16x32_f16(wf[g][3], af3, hi[g], 0, 0, 0);
        f32x4 acc = a + b;
        if (g == 2) {   // tanh gate: positive exponent
            E[g][0] = (f32x2){ fexp2( acc[0]), fexp2( acc[1]) };
            E[g][1] = (f32x2){ fexp2( acc[2]), fexp2( acc[3]) };
        } else {        // sigmoid gates: negated exponent (free src modifier)
            E[g][0] = (f32x2){ fexp2(-acc[0]), fexp2(-acc[1]) };
            E[g][1] = (f32x2){ fexp2(-acc[2]), fexp2(-acc[3]) };
        }
    }

    // ---- ew phase 2: packed-f32 pairs; C kept pre-scaled by 2log2e ----
    const f32x2 one2 = {1.0f, 1.0f};
    const f32x2 k2   = { TWOLOG2E,  TWOLOG2E};
    const f32x2 mk2  = {-TWOLOG2E, -TWOLOG2E};
    _Float16* hwp = hw + l15 * HSTRIDE + hcol0;
    #pragma unroll
    for (int p = 0; p < 2; ++p) {
        f32x2 u  = one2 + E[0][p];                               // 1+Ei
        f32x2 v  = one2 + E[1][p];                               // 1+Ef
        f32x2 w  = one2 + E[2][p];                               // 1+Eg
        f32x2 wm = __builtin_elementwise_fma(E[2][p], k2, mk2);  // 2log2e*(Eg-1)
        f32x2 uw = u * w;
        // C' = [C*u*w + wm*v] / (v*u*w)  (2log2e domain), one rcp
        f32x2 nm = __builtin_elementwise_fma(C[p], uw, wm * v);
        f32x2 dn = v * uw;
        f32x2 rd = { frcp(dn[0]), frcp(dn[1]) };
        f32x2 cn = nm * rd;
        C[p] = cn;
        f32x2 ec  = { fexp2(cn[0]), fexp2(cn[1]) };              // tanh(c') = (ec-1)/(ec+1)
        f32x2 eo1 = one2 + E[3][p];
        f32x2 den = __builtin_elementwise_fma(ec, eo1, eo1);     // (ec+1)*(1+Eo)
        f32x2 rh  = { frcp(den[0]), frcp(den[1]) };
        f32x2 hv  = __builtin_elementwise_fma(ec, rh, -rh);      // (ec-1)*rh
        // early 4 B store per pair (packed cvt): p=0 drains before p=1 retires
        h16x2 hp = __builtin_amdgcn_cvt_pkrtz(hv[0], hv[1]);
        f16x2 hh = __builtin_bit_cast(f16x2, hp);
        *(f16x2*)(hwp + 2 * p) = hh;
    }
}

__launch_bounds__(BLOCK, 2)
__global__ void lstm_fused_kernel(const float* __restrict__ x,
                                  const float* __restrict__ W_ih,
                                  const float* __restrict__ W_hh,
                                  const float* __restrict__ b_ih,
                                  const float* __restrict__ b_hh,
                                  const float* __restrict__ fc_W,
                                  const float* __restrict__ fc_b,
                                  float* __restrict__ out)
{
    __shared__ __align__(16) float xs[T + 1][XSTRIDE];           // +1 row: prefetch pad
    __shared__ __align__(16) _Float16 hb0[16 * HSTRIDE];         // h buffers (4.25 KB each)
    __shared__ __align__(16) _Float16 hb1[16 * HSTRIDE];

    const int tid  = threadIdx.x;
    const int wave = tid >> 6;          // column tile 0..7
    const int lane = tid & 63;
    const int l15  = lane & 15;         // batch row (B-operand col)
    const int q    = lane >> 4;         // 0..3
    const int hcol0 = wave * 16 + q * 4;// first of this lane's 4 hidden cols

    // ---- stage x: [b][t] global -> xs[t][b] (16 batches x 128 t) ----
    {
        const int t0 = tid & 127;
        const int bb = tid >> 7;        // 0..3
        const float* xb = x + (size_t)blockIdx.x * (16 * T);
        xs[t0][bb]      = xb[bb * T + t0];
        xs[t0][bb + 4]  = xb[(bb + 4) * T + t0];
        xs[t0][bb + 8]  = xb[(bb + 8) * T + t0];
        xs[t0][bb + 12] = xb[(bb + 12) * T + t0];
    }
    // h0 = 0 (u32-vectorized: 1088 dword stores across 512 threads)
    for (int i = tid; i < 16 * HSTRIDE / 2; i += BLOCK)
        ((unsigned int*)hb0)[i] = 0u;

    // ---- weights: fragments built directly from W_hh (prep folded in).
    // lane(l15,q), kc -> W_hh[g*H + wave*16 + l15][kc*32+q*8 ..+8], log2e-scaled
    f16x8 wf[4][4];
    f32x4 wihv[4], biasv[4];
    #pragma unroll
    for (int g = 0; g < 4; ++g) {
        const float s = (g == 2) ? TWOLOG2E : LOG2E;
        #pragma unroll
        for (int kc = 0; kc < 4; ++kc) {
            const float* src = W_hh + (size_t)(g * H + wave * 16 + l15) * H + kc * 32 + q * 8;
            float4 w0 = *(const float4*)src;
            float4 w1 = *(const float4*)(src + 4);
            f16x8 f;
            f[0] = (_Float16)(w0.x * s); f[1] = (_Float16)(w0.y * s);
            f[2] = (_Float16)(w0.z * s); f[3] = (_Float16)(w0.w * s);
            f[4] = (_Float16)(w1.x * s); f[5] = (_Float16)(w1.y * s);
            f[6] = (_Float16)(w1.z * s); f[7] = (_Float16)(w1.w * s);
            wf[g][kc] = f;
        }
        #pragma unroll
        for (int r = 0; r < 4; ++r) {   // per-lane input-proj coeffs for its 4 cols
            const int n = g * H + hcol0 + r;
            wihv[g][r]  = W_ih[n] * s;
            biasv[g][r] = (b_ih[n] + b_hh[n]) * s;
        }
    }

    f32x2 C[2] = {{0.f, 0.f}, {0.f, 0.f}};   // cell state, pre-scaled by 2log2e

    __syncthreads();

    // preacts for t=0
    f32x4 iv[4];
    {
        float xv = xs[0][l15];
        f32x4 xb = {xv, xv, xv, xv};
        #pragma unroll
        for (int g = 0; g < 4; ++g)
            iv[g] = __builtin_elementwise_fma(xb, wihv[g], biasv[g]);
    }
    const float* xpn = &xs[1][0];       // next-step preact source

    // ---- recurrence: unrolled x2, compile-time buffer bases, 1 barrier/step ----
    #pragma unroll 1
    for (int t2 = 0; t2 < T / 2; ++t2) {
        lstm_step(hb0, hb1, iv, xpn, wf, wihv, biasv, C, l15, q, hcol0);
        xpn += XSTRIDE;
        __syncthreads();
        lstm_step(hb1, hb0, iv, xpn, wf, wihv, biasv, C, l15, q, hcol0);
        xpn += XSTRIDE;
        __syncthreads();
    }
    // T even -> final h lives in hb0

    // ---- epilogue: out[b] = fc_b + sum_j fc_W[j] * hT[b][j] ----
    if (tid < 256) {
        const int b    = tid >> 4;      // 0..15
        const int part = tid & 15;
        const _Float16* hrow = &hb0[b * HSTRIDE];
        float s = 0.0f;
        #pragma unroll
        for (int i = 0; i < 8; ++i) {
            const int j = part * 8 + i;
            s += fc_W[j] * (float)hrow[j];
        }
        s += __shfl_xor(s, 8, 16);
        s += __shfl_xor(s, 4, 16);
        s += __shfl_xor(s, 2, 16);
        s += __shfl_xor(s, 1, 16);
        if (part == 0)
            out[blockIdx.x * 16 + b] = s + fc_b[0];
    }
}

extern "C" void kernel_launch(void* const* d_in, const int* in_sizes, int n_in,
                              void* d_out, int out_size, void* d_ws, size_t ws_size,
                              hipStream_t stream)
{
    const float* x    = (const float*)d_in[0];
    const float* W_ih = (const float*)d_in[1];
    const float* W_hh = (const float*)d_in[2];
    const float* b_ih = (const float*)d_in[3];
    const float* b_hh = (const float*)d_in[4];
    const float* fc_W = (const float*)d_in[5];
    const float* fc_b = (const float*)d_in[6];
    float* out = (float*)d_out;
    (void)d_ws; (void)ws_size;

    const int B = in_sizes[0] / H;         // 4096 chunks
    dim3 grid(B / 16);                     // 256 blocks -> 1 per CU
    dim3 block(BLOCK);                     // 8 waves, 2 per SIMD
    hipLaunchKernelGGL(lstm_fused_kernel, grid, block, 0, stream,
                       x, W_ih, W_hh, b_ih, b_hh, fc_W, fc_b, out);
}